// Round 8
// baseline (119.591 us; speedup 1.0000x reference)
//
#include <hip/hip_runtime.h>
#include <hip/hip_bf16.h>
#include <stdint.h>

// CausalSelfAttention: B=8, T=2048, C=128, H=4, D=32. fp32 in / fp32 out.
//   qkv_mfma: qkv = x @ w_qkv + b (Q pre-scaled log2e/sqrt(D); V -> [bh][d][t])
//   attn:     transposed-S flash attention: S^T=K*Q^T, P stays in registers,
//             PV via mfma_f32_16x16x16bf16_1k (B-frag == exp'd S^T lane layout).
//   out_mfma: out = y @ w_proj + b (fp32 out)
// ws: qb 4MB | kb 4MB | vtb 4MB | yb bf16 4MB = 16MB

#define T_SEQ 2048
#define C_EMBD 128
#define NH 4
#define HD 32
#define BATCH 8
#define BHT (BATCH * NH)

typedef float f4  __attribute__((ext_vector_type(4)));
typedef short bh8 __attribute__((ext_vector_type(8)));
typedef short bh4 __attribute__((ext_vector_type(4)));
typedef unsigned long long ull;

__device__ __forceinline__ unsigned short f2bf(float f) {
    union { float f; unsigned u; } v; v.f = f;
    return (unsigned short)((v.u + 0x7fffu + ((v.u >> 16) & 1u)) >> 16);
}
__device__ __forceinline__ unsigned pk2(float a, float b) {
    float2 t; t.x = a; t.y = b;
    __hip_bfloat162 h = __float22bfloat162_rn(t);   // v_cvt_pk_bf16_f32
    union { __hip_bfloat162 h; unsigned u; } c; c.h = h;
    return c.u;
}
__device__ __forceinline__ ull pk4(float a, float b, float c, float d) {
    return (ull)pk2(a, b) | ((ull)pk2(c, d) << 32);
}

// ---------------------------------------------------------------------------
// Kernel 1: qkv = x @ w_qkv + b_qkv via MFMA. Grid (nt=3, mt=256).
// ---------------------------------------------------------------------------
__global__ __launch_bounds__(256) void qkv_mfma(const float* __restrict__ x,
                                                const float* __restrict__ w,
                                                const float* __restrict__ bias,
                                                unsigned short* __restrict__ qb,
                                                unsigned short* __restrict__ kb,
                                                unsigned short* __restrict__ vtb) {
    constexpr int XR = 136;
    constexpr int WR = 136;
    constexpr int VR = 72;
    __shared__ __align__(16) unsigned short xs[64 * XR];
    __shared__ __align__(16) unsigned short wt[128 * WR];
    __shared__ __align__(16) unsigned short vt[128 * VR];

    const int nt = blockIdx.x;        // 0=Q 1=K 2=V
    const int mt = blockIdx.y;        // row tile of 64
    const int t0g = mt * 64;
    const int b = t0g >> 11;
    const int t0 = t0g & 2047;
    const int tid = threadIdx.x;
    const int wave = tid >> 6;
    const int lane = tid & 63;
    const int col = lane & 15;
    const int quad = lane >> 4;

    for (int i = 0; i < 8; ++i) {
        const int idx = tid + i * 256;
        const int row = idx >> 5, c4 = idx & 31;
        const float4 xv = *(const float4*)(x + (size_t)(t0g + row) * C_EMBD + c4 * 4);
        *(ull*)(&xs[row * XR + c4 * 4]) = pk4(xv.x, xv.y, xv.z, xv.w);
    }
    for (int i = 0; i < 16; ++i) {
        const int idx = tid + i * 256;
        const int n = idx & 127, k4 = idx >> 7;
        const float w0 = w[(k4 * 4 + 0) * 384 + nt * 128 + n];
        const float w1 = w[(k4 * 4 + 1) * 384 + nt * 128 + n];
        const float w2 = w[(k4 * 4 + 2) * 384 + nt * 128 + n];
        const float w3 = w[(k4 * 4 + 3) * 384 + nt * 128 + n];
        *(ull*)(&wt[n * WR + k4 * 4]) = pk4(w0, w1, w2, w3);
    }
    __syncthreads();

    f4 acc[8];
#pragma unroll
    for (int nf = 0; nf < 8; ++nf) {
        const float bv = bias[nt * 128 + nf * 16 + col];
        acc[nf] = (f4){bv, bv, bv, bv};
    }
#pragma unroll
    for (int ch = 0; ch < 4; ++ch) {
        const bh8 af = *(const bh8*)(&xs[(wave * 16 + col) * XR + ch * 32 + quad * 8]);
#pragma unroll
        for (int nf = 0; nf < 8; ++nf) {
            const bh8 bf = *(const bh8*)(&wt[(nf * 16 + col) * WR + ch * 32 + quad * 8]);
            acc[nf] = __builtin_amdgcn_mfma_f32_16x16x32_bf16(af, bf, acc[nf], 0, 0, 0);
        }
    }

    const int mrow = wave * 16 + quad * 4;
    if (nt < 2) {
        unsigned short* outp = (nt == 0) ? qb : kb;
        const float sc = (nt == 0) ? 0.25503485952317864f : 1.0f;  // log2(e)/sqrt(32)
#pragma unroll
        for (int nf = 0; nf < 8; ++nf) {
            const int n = nf * 16 + col, h = n >> 5, d = n & 31;
            const size_t base = ((size_t)(b * NH + h) * T_SEQ + t0 + mrow) * HD + d;
#pragma unroll
            for (int r = 0; r < 4; ++r)
                outp[base + (size_t)r * HD] = f2bf(acc[nf][r] * sc);
        }
    } else {
#pragma unroll
        for (int nf = 0; nf < 8; ++nf) {
            const int n = nf * 16 + col;
            *(ull*)(&vt[n * VR + mrow]) = pk4(acc[nf][0], acc[nf][1], acc[nf][2], acc[nf][3]);
        }
        __syncthreads();
        for (int i = 0; i < 16; ++i) {
            const int idx = tid + i * 256;
            const int c = idx >> 5, dw = idx & 31;
            const int h2 = c >> 5, d2 = c & 31;
            const unsigned v0 = *(const unsigned*)(&vt[c * VR + dw * 2]);
            *(unsigned*)(vtb + ((size_t)(b * NH + h2) * HD + d2) * T_SEQ + t0 + dw * 2) = v0;
        }
    }
}

// ---------------------------------------------------------------------------
// Kernel 2: transposed-S MFMA flash attention, q-tile 128, K-tile 64.
// S^T = mfma_16x16x32(kfrag, qfrag): lane holds P^T[key=quad*4+r][query=col]
// == B-operand layout of mfma_f32_16x16x16bf16_1k -> PV with P in registers.
// outT = V^T * P^T: D[dim=quad*4+r][query=col] -> packed b64 y stores.
// Grid 512: bid<256 -> qt=15-(bid>>5) (heavy), else qt=(bid>>5)-8; round-robin
// co-residency pairs heavy+light (36 intervals/CU const).
// ---------------------------------------------------------------------------
__global__ __launch_bounds__(256, 2) void attn(const unsigned short* __restrict__ qb,
                                               const unsigned short* __restrict__ kb,
                                               const unsigned short* __restrict__ vtb,
                                               unsigned short* __restrict__ y) {
    constexpr int KROW = 40;  // 80B rows, 16B-aligned
    constexpr int VROW = 72;  // 144B rows, 16B-aligned, add-swizzled 8-elem blocks
    __shared__ __align__(16) unsigned short Ks[2][64 * KROW];
    __shared__ __align__(16) unsigned short Vt[2][32 * VROW];

    const int bid = blockIdx.x;
    const int bh = bid & 31;
    const int g = bid >> 5;
    const int qt = (g < 8) ? (15 - g) : (g - 8);
    const int tid = threadIdx.x;
    const int wave = tid >> 6;
    const int lane = tid & 63;
    const int col = lane & 15;
    const int quad = lane >> 4;
    const int q0 = qt * 128;
    const int ntiles = 2 * qt + 2;

    const unsigned short* kbase = kb + (size_t)bh * T_SEQ * HD;
    const unsigned short* vbase = vtb + (size_t)bh * HD * T_SEQ;
    const int ks_t = tid >> 2, ks_q = tid & 3;
    const int vs_d = tid >> 3, vs_s = tid & 7;
    const int vsw = (vs_s + 2 * (vs_d & 7)) & 7;  // swizzled 8-elem block

    // Q fragments (B-operand of S^T): queries q0 + wave*32 + mi*16 + col
    bh8 qfrag[2];
#pragma unroll
    for (int mi = 0; mi < 2; ++mi)
        qfrag[mi] = *(const bh8*)(qb + ((size_t)bh * T_SEQ + q0 + wave * 32 + mi * 16 + col) * HD + quad * 8);

    f4 yacc[2][2];
#pragma unroll
    for (int mi = 0; mi < 2; ++mi)
#pragma unroll
        for (int dh = 0; dh < 2; ++dh) yacc[mi][dh] = (f4){0.f, 0.f, 0.f, 0.f};
    float lsum[2] = {0.f, 0.f};

    uint4 kreg = *(const uint4*)(kbase + (size_t)ks_t * HD + ks_q * 8);
    uint4 vreg = *(const uint4*)(vbase + (size_t)vs_d * T_SEQ + vs_s * 8);

    for (int kt = 0; kt < ntiles; ++kt) {
        const int buf = kt & 1;
        *(uint4*)(&Ks[buf][ks_t * KROW + ks_q * 8]) = kreg;
        *(uint4*)(&Vt[buf][vs_d * VROW + vsw * 8]) = vreg;
        if (kt + 1 < ntiles) {
            kreg = *(const uint4*)(kbase + (size_t)((kt + 1) * 64 + ks_t) * HD + ks_q * 8);
            vreg = *(const uint4*)(vbase + (size_t)vs_d * T_SEQ + (kt + 1) * 64 + vs_s * 8);
        }
        __syncthreads();

        // hoisted K and V^T fragments (shared by both query halves)
        bh8 kf[4];
        bh4 vf[4][2];
#pragma unroll
        for (int f = 0; f < 4; ++f) {
            kf[f] = *(const bh8*)(&Ks[buf][(f * 16 + col) * KROW + quad * 8]);
            const int blk = ((f * 2 + (quad >> 1)) + 2 * (col & 7)) & 7;
            const int off = blk * 8 + (quad & 1) * 4;
            vf[f][0] = *(const bh4*)(&Vt[buf][col * VROW + off]);
            vf[f][1] = *(const bh4*)(&Vt[buf][(col + 16) * VROW + off]);
        }

        const int dz = kt - 2 * qt;   // >= 0: diagonal zone (lk0 = dz*64)
#pragma unroll
        for (int mi = 0; mi < 2; ++mi) {
            const int qb0 = wave * 32 + mi * 16;
#pragma unroll
            for (int f = 0; f < 4; ++f) {
                bool edge = false;
                if (dz >= 0) {
                    const int lkb = dz * 64 + f * 16;
                    if (lkb > qb0) continue;      // whole chunk masked
                    edge = (lkb == qb0);
                }
                f4 z = {0.f, 0.f, 0.f, 0.f};
                z = __builtin_amdgcn_mfma_f32_16x16x32_bf16(kf[f], qfrag[mi], z, 0, 0, 0);
                float p[4];
#pragma unroll
                for (int r = 0; r < 4; ++r) {
                    const float e = __builtin_amdgcn_exp2f(z[r]);
                    p[r] = (edge && (quad * 4 + r > col)) ? 0.f : e;
                }
                lsum[mi] += p[0] + p[1] + p[2] + p[3];
                union { unsigned u[2]; bh4 v; } pf;
                pf.u[0] = pk2(p[0], p[1]);
                pf.u[1] = pk2(p[2], p[3]);
                yacc[mi][0] = __builtin_amdgcn_mfma_f32_16x16x16bf16_1k(vf[f][0], pf.v, yacc[mi][0], 0, 0, 0);
                yacc[mi][1] = __builtin_amdgcn_mfma_f32_16x16x16bf16_1k(vf[f][1], pf.v, yacc[mi][1], 0, 0, 0);
            }
        }
    }

    // epilogue: l reduction over quads (lanes col, col+16, col+32, col+48)
    const int bb = bh >> 2, hh = bh & 3;
#pragma unroll
    for (int mi = 0; mi < 2; ++mi) {
        float t = lsum[mi];
        t += __shfl_xor(t, 16);
        t += __shfl_xor(t, 32);
        const float inv = 1.0f / t;
        const size_t row = (size_t)bb * T_SEQ + q0 + wave * 32 + mi * 16 + col;
#pragma unroll
        for (int dh = 0; dh < 2; ++dh) {
            *(ull*)(y + row * C_EMBD + hh * HD + dh * 16 + quad * 4) =
                pk4(yacc[mi][dh][0] * inv, yacc[mi][dh][1] * inv,
                    yacc[mi][dh][2] * inv, yacc[mi][dh][3] * inv);
        }
    }
}

// ---------------------------------------------------------------------------
// Kernel 3: out = y @ w_proj + b_proj via MFMA. Grid 256.
// ---------------------------------------------------------------------------
__global__ __launch_bounds__(256) void out_mfma(const unsigned short* __restrict__ y,
                                                const float* __restrict__ w,
                                                const float* __restrict__ bias,
                                                float* __restrict__ out) {
    constexpr int YR = 136;
    constexpr int WR = 136;
    __shared__ __align__(16) unsigned short ys[64 * YR];
    __shared__ __align__(16) unsigned short wt[128 * WR];

    const int mt = blockIdx.x;
    const int row0 = mt * 64;
    const int tid = threadIdx.x;
    const int wave = tid >> 6;
    const int lane = tid & 63;
    const int col = lane & 15;
    const int quad = lane >> 4;

    for (int i = 0; i < 4; ++i) {
        const int idx = tid + i * 256;
        const int row = idx >> 4, q8 = idx & 15;
        const uint4 v = *(const uint4*)(y + (size_t)(row0 + row) * C_EMBD + q8 * 8);
        *(uint4*)(&ys[row * YR + q8 * 8]) = v;
    }
    for (int i = 0; i < 16; ++i) {
        const int idx = tid + i * 256;
        const int n = idx & 127, k4 = idx >> 7;
        const float w0 = w[(k4 * 4 + 0) * C_EMBD + n];
        const float w1 = w[(k4 * 4 + 1) * C_EMBD + n];
        const float w2 = w[(k4 * 4 + 2) * C_EMBD + n];
        const float w3 = w[(k4 * 4 + 3) * C_EMBD + n];
        *(ull*)(&wt[n * WR + k4 * 4]) = pk4(w0, w1, w2, w3);
    }
    __syncthreads();

    f4 acc[8];
#pragma unroll
    for (int nf = 0; nf < 8; ++nf) {
        const float bv = bias[nf * 16 + col];
        acc[nf] = (f4){bv, bv, bv, bv};
    }
#pragma unroll
    for (int ch = 0; ch < 4; ++ch) {
        const bh8 af = *(const bh8*)(&ys[(wave * 16 + col) * YR + ch * 32 + quad * 8]);
#pragma unroll
        for (int nf = 0; nf < 8; ++nf) {
            const bh8 bf = *(const bh8*)(&wt[(nf * 16 + col) * WR + ch * 32 + quad * 8]);
            acc[nf] = __builtin_amdgcn_mfma_f32_16x16x32_bf16(af, bf, acc[nf], 0, 0, 0);
        }
    }

    const int mrow = wave * 16 + quad * 4;
#pragma unroll
    for (int nf = 0; nf < 8; ++nf)
#pragma unroll
        for (int r = 0; r < 4; ++r)
            out[(size_t)(row0 + mrow + r) * C_EMBD + nf * 16 + col] = acc[nf][r];
}

extern "C" void kernel_launch(void* const* d_in, const int* in_sizes, int n_in,
                              void* d_out, int out_size, void* d_ws, size_t ws_size,
                              hipStream_t stream) {
    const float* x      = (const float*)d_in[0];
    const float* w_qkv  = (const float*)d_in[1];
    const float* b_qkv  = (const float*)d_in[2];
    const float* w_proj = (const float*)d_in[3];
    const float* b_proj = (const float*)d_in[4];
    float* out = (float*)d_out;

    unsigned short* qb  = (unsigned short*)d_ws;                   // 4 MB
    unsigned short* kb  = qb + (size_t)BHT * T_SEQ * HD;           // 4 MB
    unsigned short* vtb = kb + (size_t)BHT * T_SEQ * HD;           // 4 MB
    unsigned short* yb  = vtb + (size_t)BHT * T_SEQ * HD;          // 4 MB (bf16 y)

    qkv_mfma<<<dim3(3, 256), 256, 0, stream>>>(x, w_qkv, b_qkv, qb, kb, vtb);
    attn<<<512, 256, 0, stream>>>(qb, kb, vtb, yb);
    out_mfma<<<256, 256, 0, stream>>>(yb, w_proj, b_proj, out);
}